// Round 1
// baseline (234.865 us; speedup 1.0000x reference)
//
#include <hip/hip_runtime.h>
#include <hip/hip_bf16.h>
#include <math.h>

#define DIM 512
#define NH 8
#define HD 64
#define TT 1024
#define CH 16      // chunks per (b,h) sequence
#define CL 64      // chunk length (CH*CL == TT)
#define EPSF 1e-5f

// online logsumexp update: state (M,S) represents sum = S * exp(M)
__device__ __forceinline__ void lse_update(float &M, float &S, float e) {
    float nm = fmaxf(M, e);
    S = fmaf(S, __expf(M - nm), __expf(e - nm));
    M = nm;
}

// ---------------- Kernel 1: fused QKV projection + activations ----------------
// grid: (NH colTiles, rowTiles, 3)  block: 256
// z=0 -> Qf=softplus(q/temp), z=1 -> Kf=softplus(k/temp), z=2 -> Vv raw
// outputs in (b,h,t,n) layout
__launch_bounds__(256)
__global__ void k_gemm_qkv(const float* __restrict__ x,
                           const float* __restrict__ wq, const float* __restrict__ bq,
                           const float* __restrict__ wk, const float* __restrict__ bk,
                           const float* __restrict__ wv, const float* __restrict__ bv,
                           const float* __restrict__ lbeta, const float* __restrict__ ltemp,
                           float* __restrict__ Qf, float* __restrict__ Kf, float* __restrict__ Vv)
{
    const int z = blockIdx.z;
    const float* __restrict__ w    = (z == 0) ? wq : (z == 1) ? wk : wv;
    const float* __restrict__ bias = (z == 0) ? bq : (z == 1) ? bk : bv;
    const int h = blockIdx.x;              // col tile == head (64 cols)
    const int rowBase = blockIdx.y * 64;
    const int colBase = h * 64;

    __shared__ __align__(16) float As[16][68];   // transposed x tile [k][row], padded
    __shared__ __align__(16) float Bs[16][64];   // w tile [k][col]

    const int tid = threadIdx.x;
    const int ty = tid >> 4, tx = tid & 15;
    const int r0 = ty * 4, c0 = tx * 4;
    const int ar = tid >> 2, ak = (tid & 3) * 4;
    const int bkr = tid >> 4, bc = (tid & 15) * 4;

    float acc[4][4] = {};

    for (int k0 = 0; k0 < DIM; k0 += 16) {
        float4 av = *(const float4*)&x[(size_t)(rowBase + ar) * DIM + k0 + ak];
        As[ak + 0][ar] = av.x; As[ak + 1][ar] = av.y;
        As[ak + 2][ar] = av.z; As[ak + 3][ar] = av.w;
        *(float4*)&Bs[bkr][bc] = *(const float4*)&w[(size_t)(k0 + bkr) * DIM + colBase + bc];
        __syncthreads();
#pragma unroll
        for (int kk = 0; kk < 16; kk++) {
            float4 a = *(const float4*)&As[kk][r0];
            float4 b = *(const float4*)&Bs[kk][c0];
            float aa[4] = {a.x, a.y, a.z, a.w};
            float bb[4] = {b.x, b.y, b.z, b.w};
#pragma unroll
            for (int i = 0; i < 4; i++)
#pragma unroll
                for (int j = 0; j < 4; j++)
                    acc[i][j] = fmaf(aa[i], bb[j], acc[i][j]);
        }
        __syncthreads();
    }

    float b4[4] = { bias[colBase + c0 + 0], bias[colBase + c0 + 1],
                    bias[colBase + c0 + 2], bias[colBase + c0 + 3] };

    if (z == 2) {
#pragma unroll
        for (int i = 0; i < 4; i++) {
            int rr = rowBase + r0 + i;
            int bbn = rr >> 10, t = rr & (TT - 1);
            float4 o;
            o.x = acc[i][0] + b4[0]; o.y = acc[i][1] + b4[1];
            o.z = acc[i][2] + b4[2]; o.w = acc[i][3] + b4[3];
            *(float4*)&Vv[(((size_t)(bbn * NH + h)) * TT + t) * HD + c0] = o;
        }
    } else {
        float beta = expf(lbeta[h]);
        float invb = 1.0f / beta;
        float itemp = 1.0f / expf(ltemp[h]);
        float* __restrict__ dst = (z == 0) ? Qf : Kf;
#pragma unroll
        for (int i = 0; i < 4; i++) {
            int rr = rowBase + r0 + i;
            int bbn = rr >> 10, t = rr & (TT - 1);
            float v4[4];
#pragma unroll
            for (int j = 0; j < 4; j++) {
                float val = (acc[i][j] + b4[j]) * itemp;
                float zz = beta * val;
                // stable softplus: (max(z,0)+log1p(exp(-|z|)))/beta
                v4[j] = (fmaxf(zz, 0.f) + log1pf(expf(-fabsf(zz)))) * invb;
            }
            float4 o = { v4[0], v4[1], v4[2], v4[3] };
            *(float4*)&dst[(((size_t)(bbn * NH + h)) * TT + t) * HD + c0] = o;
        }
    }
}

// ---------------- Kernel 2: per-chunk local reduction ----------------
// grid: (CH, NH, B)  block: 256.  thread (g=tid>>6, q=tid&63) owns p in [16g,16g+16), n=q
__launch_bounds__(256)
__global__ void k_chunk_reduce(const float* __restrict__ Kf, const float* __restrict__ Vv,
                               float* __restrict__ aAM, float* __restrict__ aAS,
                               float* __restrict__ aDM, float* __restrict__ aDS,
                               float* __restrict__ aCM)
{
    const int c = blockIdx.x;
    const int bh = blockIdx.z * NH + blockIdx.y;
    const int tid = threadIdx.x;

    __shared__ __align__(16) float sK[CL * HD];
    __shared__ __align__(16) float sV[CL * HD];
    __shared__ __align__(16) float sM0[CL * HD];

    size_t base = ((size_t)bh * TT + (size_t)c * CL) * HD;
    const float4* K4 = (const float4*)(Kf + base);
    const float4* V4 = (const float4*)(Vv + base);
#pragma unroll
    for (int r = 0; r < 4; r++) {
        int f = tid + 256 * r;
        float4 kv = K4[f];
        ((float4*)sK)[f] = kv;
        float4 m;
        m.x = __logf(kv.x + EPSF); m.y = __logf(kv.y + EPSF);
        m.z = __logf(kv.z + EPSF); m.w = __logf(kv.w + EPSF);
        ((float4*)sM0)[f] = m;
        ((float4*)sV)[f] = V4[f];
    }
    __syncthreads();

    const int q = tid & 63, g = tid >> 6, p0 = g * 16;
    float M[16], S[16];
#pragma unroll
    for (int j = 0; j < 16; j++) { M[j] = -INFINITY; S[j] = 0.f; }
    float MD = -INFINITY, SD = 0.f, cmx = 0.f;

    for (int s = 0; s < CL; s++) {
        float kq = sK[s * HD + q];
#pragma unroll
        for (int j4 = 0; j4 < 4; j4++) {
            float4 vv = *(const float4*)&sV[s * HD + p0 + j4 * 4];
            float4 mm = *(const float4*)&sM0[s * HD + p0 + j4 * 4];
            lse_update(M[j4 * 4 + 0], S[j4 * 4 + 0], fmaf(vv.x, kq, mm.x));
            lse_update(M[j4 * 4 + 1], S[j4 * 4 + 1], fmaf(vv.y, kq, mm.y));
            lse_update(M[j4 * 4 + 2], S[j4 * 4 + 2], fmaf(vv.z, kq, mm.z));
            lse_update(M[j4 * 4 + 3], S[j4 * 4 + 3], fmaf(vv.w, kq, mm.w));
        }
        if (tid < 64) {
            float m0q = sM0[s * HD + q];
            lse_update(MD, SD, kq + m0q);
            cmx = fmaxf(cmx, kq + EPSF);
        }
    }

    size_t abase = ((size_t)bh * CH + c) * 4096;
#pragma unroll
    for (int j = 0; j < 16; j++) {
        aAM[abase + (size_t)(p0 + j) * HD + q] = M[j];
        aAS[abase + (size_t)(p0 + j) * HD + q] = S[j];
    }
    if (tid < 64) {
        size_t dbase = ((size_t)bh * CH + c) * HD + q;
        aDM[dbase] = MD; aDS[dbase] = SD; aCM[dbase] = cmx;
    }
}

// ---------------- Kernel 3: exclusive scan of chunk aggregates ----------------
__global__ void k_scan_agg(float* __restrict__ aAM, float* __restrict__ aAS,
                           float* __restrict__ aDM, float* __restrict__ aDS,
                           float* __restrict__ aCM, int BH)
{
    int idx = blockIdx.x * 256 + threadIdx.x;
    int nA = BH * 4096, nD = BH * 64;
    if (idx < nA) {
        int bh = idx >> 12, pn = idx & 4095;
        float Mr = -INFINITY, Sr = 0.f;
        for (int c = 0; c < CH; c++) {
            size_t off = ((size_t)bh * CH + c) * 4096 + pn;
            float Mc = aAM[off], Sc = aAS[off];
            aAM[off] = Mr; aAS[off] = Sr;
            float nm = fmaxf(Mr, Mc);
            Sr = fmaf(Sr, __expf(Mr - nm), Sc * __expf(Mc - nm));
            Mr = nm;
        }
    } else if (idx < nA + nD) {
        int i = idx - nA; int bh = i >> 6, n = i & 63;
        float Mr = -INFINITY, Sr = 0.f;
        for (int c = 0; c < CH; c++) {
            size_t off = ((size_t)bh * CH + c) * HD + n;
            float Mc = aDM[off], Sc = aDS[off];
            aDM[off] = Mr; aDS[off] = Sr;
            float nm = fmaxf(Mr, Mc);
            Sr = fmaf(Sr, __expf(Mr - nm), Sc * __expf(Mc - nm));
            Mr = nm;
        }
    } else if (idx < nA + 2 * nD) {
        int i = idx - nA - nD; int bh = i >> 6, n = i & 63;
        float r = 0.f;
        for (int c = 0; c < CH; c++) {
            size_t off = ((size_t)bh * CH + c) * HD + n;
            float v = aCM[off];
            aCM[off] = r;
            r = fmaxf(r, v);
        }
    }
}

// ---------------- Kernel 4: within-chunk rescan + output Y ----------------
__launch_bounds__(256)
__global__ void k_chunk_out(const float* __restrict__ Kf, const float* __restrict__ Vv,
                            const float* __restrict__ Qf,
                            const float* __restrict__ aAM, const float* __restrict__ aAS,
                            const float* __restrict__ aDM, const float* __restrict__ aDS,
                            const float* __restrict__ aCM,
                            const float* __restrict__ lsharp, float* __restrict__ Ym)
{
    const int c = blockIdx.x, hh = blockIdx.y, bb = blockIdx.z;
    const int bh = bb * NH + hh;
    const int tid = threadIdx.x;

    __shared__ __align__(16) float sK[CL * HD];
    __shared__ __align__(16) float sV[CL * HD];
    __shared__ __align__(16) float sM0[CL * HD];
    __shared__ __align__(16) float sQ[CL * HD];
    __shared__ float partial[256];

    size_t base = ((size_t)bh * TT + (size_t)c * CL) * HD;
    const float4* K4 = (const float4*)(Kf + base);
    const float4* V4 = (const float4*)(Vv + base);
    const float4* Q4 = (const float4*)(Qf + base);
#pragma unroll
    for (int r = 0; r < 4; r++) {
        int f = tid + 256 * r;
        float4 kv = K4[f];
        ((float4*)sK)[f] = kv;
        float4 m;
        m.x = __logf(kv.x + EPSF); m.y = __logf(kv.y + EPSF);
        m.z = __logf(kv.z + EPSF); m.w = __logf(kv.w + EPSF);
        ((float4*)sM0)[f] = m;
        ((float4*)sV)[f] = V4[f];
        ((float4*)sQ)[f] = Q4[f];
    }
    __syncthreads();

    const int q = tid & 63, g = tid >> 6, p0 = g * 16;
    float M[16], S[16];
    size_t abase = ((size_t)bh * CH + c) * 4096;
#pragma unroll
    for (int j = 0; j < 16; j++) {
        M[j] = aAM[abase + (size_t)(p0 + j) * HD + q];
        S[j] = aAS[abase + (size_t)(p0 + j) * HD + q];
    }
    float MD = -INFINITY, SD = 0.f, cmx = 0.f;
    if (tid < 64) {
        size_t dbase = ((size_t)bh * CH + c) * HD + q;
        MD = aDM[dbase]; SD = aDS[dbase]; cmx = aCM[dbase];
    }
    const float sharp = expf(lsharp[hh]);
    const float invT = 1.0f / (float)TT;

    for (int s = 0; s < CL; s++) {
        float kq = sK[s * HD + q];
        float part = 0.f;
#pragma unroll
        for (int j4 = 0; j4 < 4; j4++) {
            float4 vv = *(const float4*)&sV[s * HD + p0 + j4 * 4];
            float4 mm = *(const float4*)&sM0[s * HD + p0 + j4 * 4];
            float4 qv = *(const float4*)&sQ[s * HD + p0 + j4 * 4];
#define STEPJ(compo, jj) { \
            lse_update(M[jj], S[jj], fmaf(vv.compo, kq, mm.compo)); \
            part = fmaf(qv.compo, M[jj] + __logf(S[jj]), part); }
            STEPJ(x, j4 * 4 + 0)
            STEPJ(y, j4 * 4 + 1)
            STEPJ(z, j4 * 4 + 2)
            STEPJ(w, j4 * 4 + 3)
#undef STEPJ
        }
        partial[tid] = part;
        float t1 = 0.f, t2 = 0.f;
        if (tid < 64) {
            float m0q = sM0[s * HD + q];
            lse_update(MD, SD, kq + m0q);
            cmx = fmaxf(cmx, kq + EPSF);
            float ld = MD + __logf(SD);
            float mc = __logf(cmx);
            float qf = sQ[s * HD + q];
            t1 = qf * mc;   // per-lane term of c1 = sum_p Qf[p]*m_c[p]
            t2 = qf * ld;   // per-lane term of sum_p Qf[p]*log A_D[p]
#pragma unroll
            for (int off = 32; off >= 1; off >>= 1) {
                t1 += __shfl_xor(t1, off);
                t2 += __shfl_xor(t2, off);
            }
        }
        __syncthreads();
        if (tid < 64) {
            float num = partial[q] + partial[64 + q] + partial[128 + q] + partial[192 + q] - t1;
            float den = t2 - t1 + EPSF;
            float yv = num / den;
            float ay = __powf(fabsf(yv), sharp);
            int tg = c * CL + s;
            float outv = copysignf(ay, yv) * ((float)(tg + 1) * invT);
            Ym[((size_t)(bb * TT + tg)) * DIM + hh * HD + q] = outv;
        }
        __syncthreads();
    }
}

// ---------------- Kernel 5: output projection ----------------
__launch_bounds__(256)
__global__ void k_gemm_out(const float* __restrict__ A, const float* __restrict__ w,
                           const float* __restrict__ bias, float* __restrict__ out)
{
    const int rowBase = blockIdx.y * 64;
    const int colBase = blockIdx.x * 64;
    __shared__ __align__(16) float As[16][68];
    __shared__ __align__(16) float Bs[16][64];
    const int tid = threadIdx.x;
    const int ty = tid >> 4, tx = tid & 15;
    const int r0 = ty * 4, c0 = tx * 4;
    const int ar = tid >> 2, ak = (tid & 3) * 4;
    const int bkr = tid >> 4, bc = (tid & 15) * 4;

    float acc[4][4] = {};
    for (int k0 = 0; k0 < DIM; k0 += 16) {
        float4 av = *(const float4*)&A[(size_t)(rowBase + ar) * DIM + k0 + ak];
        As[ak + 0][ar] = av.x; As[ak + 1][ar] = av.y;
        As[ak + 2][ar] = av.z; As[ak + 3][ar] = av.w;
        *(float4*)&Bs[bkr][bc] = *(const float4*)&w[(size_t)(k0 + bkr) * DIM + colBase + bc];
        __syncthreads();
#pragma unroll
        for (int kk = 0; kk < 16; kk++) {
            float4 a = *(const float4*)&As[kk][r0];
            float4 b = *(const float4*)&Bs[kk][c0];
            float aa[4] = {a.x, a.y, a.z, a.w};
            float bb[4] = {b.x, b.y, b.z, b.w};
#pragma unroll
            for (int i = 0; i < 4; i++)
#pragma unroll
                for (int j = 0; j < 4; j++)
                    acc[i][j] = fmaf(aa[i], bb[j], acc[i][j]);
        }
        __syncthreads();
    }
    float b4[4] = { bias[colBase + c0 + 0], bias[colBase + c0 + 1],
                    bias[colBase + c0 + 2], bias[colBase + c0 + 3] };
#pragma unroll
    for (int i = 0; i < 4; i++) {
        int rr = rowBase + r0 + i;
        float4 o;
        o.x = acc[i][0] + b4[0]; o.y = acc[i][1] + b4[1];
        o.z = acc[i][2] + b4[2]; o.w = acc[i][3] + b4[3];
        *(float4*)&out[(size_t)rr * DIM + colBase + c0] = o;
    }
}

extern "C" void kernel_launch(void* const* d_in, const int* in_sizes, int n_in,
                              void* d_out, int out_size, void* d_ws, size_t ws_size,
                              hipStream_t stream)
{
    const float* x  = (const float*)d_in[0];
    const float* wq = (const float*)d_in[1];
    const float* bq = (const float*)d_in[2];
    const float* wk = (const float*)d_in[3];
    const float* bk = (const float*)d_in[4];
    const float* wv = (const float*)d_in[5];
    const float* bv = (const float*)d_in[6];
    const float* wo = (const float*)d_in[7];
    const float* bo = (const float*)d_in[8];
    const float* lb = (const float*)d_in[9];
    const float* lt = (const float*)d_in[10];
    const float* ls = (const float*)d_in[11];

    const int B  = in_sizes[0] / (TT * DIM);   // 2
    const int BH = B * NH;                     // 16

    float* ws  = (float*)d_ws;
    float* Qf  = ws;
    float* Kf  = Qf  + (size_t)BH * TT * HD;
    float* Vv  = Kf  + (size_t)BH * TT * HD;
    float* Ym  = Vv  + (size_t)BH * TT * HD;
    float* aAM = Ym  + (size_t)B * TT * DIM;
    float* aAS = aAM + (size_t)BH * CH * 4096;
    float* aDM = aAS + (size_t)BH * CH * 4096;
    float* aDS = aDM + (size_t)BH * CH * HD;
    float* aCM = aDS + (size_t)BH * CH * HD;

    dim3 g1(NH, (B * TT) / 64, 3);
    k_gemm_qkv<<<g1, 256, 0, stream>>>(x, wq, bq, wk, bk, wv, bv, lb, lt, Qf, Kf, Vv);

    dim3 g2(CH, NH, B);
    k_chunk_reduce<<<g2, 256, 0, stream>>>(Kf, Vv, aAM, aAS, aDM, aDS, aCM);

    int ntot = BH * 4096 + 2 * BH * 64;
    k_scan_agg<<<(ntot + 255) / 256, 256, 0, stream>>>(aAM, aAS, aDM, aDS, aCM, BH);

    k_chunk_out<<<g2, 256, 0, stream>>>(Kf, Vv, Qf, aAM, aAS, aDM, aDS, aCM, ls, Ym);

    dim3 g5(NH, (B * TT) / 64, 1);
    k_gemm_out<<<g5, 256, 0, stream>>>(Ym, wo, bo, (float*)d_out);
}